// Round 1
// baseline (313.845 us; speedup 1.0000x reference)
//
#include <hip/hip_runtime.h>

#define NNODES   50000
#define NHEADS   8
#define NCHAN    16
#define ATT_NORM 4.0f
#define EPS_V    1e-12f

// Pass 1: per-(edge,head) L2 norm of x_j, segment-max into node_max via
// unsigned atomicMax (valid because norms are >= 0: IEEE754 order == uint order).
__global__ void lips_pass1(const float* __restrict__ x_j,
                           const int* __restrict__ index,
                           unsigned int* __restrict__ node_max,
                           int EH) {
    int t = blockIdx.x * blockDim.x + threadIdx.x;
    if (t >= EH) return;
    const int e = t >> 3;   // / NHEADS
    const int h = t & 7;    // % NHEADS

    const float4* p = (const float4*)(x_j + (size_t)t * NCHAN);
    float4 a = p[0], b = p[1], c = p[2], d = p[3];
    float s = a.x*a.x + a.y*a.y + a.z*a.z + a.w*a.w
            + b.x*b.x + b.y*b.y + b.z*b.z + b.w*b.w
            + c.x*c.x + c.y*c.y + c.z*c.z + c.w*c.w
            + d.x*d.x + d.y*d.y + d.z*d.z + d.w*d.w;
    float nj = sqrtf(s);

    int node = index[e];
    atomicMax(node_max + (size_t)node * NHEADS + h, __float_as_uint(nj));
}

// Pass 2: recompute ni from x_i, gather node max, divide.
__global__ void lips_pass2(const float* __restrict__ e_ij,
                           const float* __restrict__ x_i,
                           const int* __restrict__ index,
                           const unsigned int* __restrict__ node_max,
                           float* __restrict__ out,
                           int EH) {
    int t = blockIdx.x * blockDim.x + threadIdx.x;
    if (t >= EH) return;
    const int e = t >> 3;
    const int h = t & 7;

    const float4* p = (const float4*)(x_i + (size_t)t * NCHAN);
    float4 a = p[0], b = p[1], c = p[2], d = p[3];
    float s = a.x*a.x + a.y*a.y + a.z*a.z + a.w*a.w
            + b.x*b.x + b.y*b.y + b.z*b.z + b.w*b.w
            + c.x*c.x + c.y*c.y + c.z*c.z + c.w*c.w
            + d.x*d.x + d.y*d.y + d.z*d.z + d.w*d.w;
    float ni = sqrtf(s);

    int node = index[e];
    float mnj = __uint_as_float(node_max[(size_t)node * NHEADS + h]);

    float denom = ATT_NORM * (ni + mnj);
    denom = fmaxf(denom, EPS_V);

    float ev = e_ij[t];
    ev = fminf(fmaxf(ev, -10000.0f), 10000.0f);
    out[t] = ev / denom;
}

extern "C" void kernel_launch(void* const* d_in, const int* in_sizes, int n_in,
                              void* d_out, int out_size, void* d_ws, size_t ws_size,
                              hipStream_t stream) {
    const float* e_ij  = (const float*)d_in[0];
    const float* x_i   = (const float*)d_in[1];
    const float* x_j   = (const float*)d_in[2];
    const int*   index = (const int*)d_in[3];

    float* out = (float*)d_out;
    unsigned int* node_max = (unsigned int*)d_ws;   // [NNODES][NHEADS]

    const int EH = out_size;                        // E * NHEADS = 12.8M
    const int threads = 256;
    const int blocks = (EH + threads - 1) / threads;

    // Zero the segment-max scratch every call (harness does not re-poison).
    hipMemsetAsync(node_max, 0, (size_t)NNODES * NHEADS * sizeof(unsigned int), stream);

    lips_pass1<<<blocks, threads, 0, stream>>>(x_j, index, node_max, EH);
    lips_pass2<<<blocks, threads, 0, stream>>>(e_ij, x_i, index, node_max, out, EH);
}